// Round 16
// baseline (147.954 us; speedup 1.0000x reference)
//
#include <hip/hip_runtime.h>
#include <hip/hip_cooperative_groups.h>

// AdaPT_Linear: per-tensor int8 quantized linear.
// out = (qx @ qw^T).f32 / (sa*sw) + qb.f32/sb
// x: [16384,1024] f32, w: [1024,1024] f32, b: [1024] f32, out: [16384,1024] f32

#define M_ROWS 16384
#define K_DIM  1024
#define N_OUT  1024

typedef int v4i __attribute__((ext_vector_type(4)));
typedef float v4f __attribute__((ext_vector_type(4)));

namespace cg = cooperative_groups;

__device__ __forceinline__ void gload_lds16(const void* g, void* l) {
  __builtin_amdgcn_global_load_lds(
      (const __attribute__((address_space(1))) void*)g,
      (__attribute__((address_space(3))) void*)l, 16, 0, 0);
}

__device__ __forceinline__ float block_reduce_max4(float m, float* red) {
#pragma unroll
  for (int off = 32; off > 0; off >>= 1)
    m = fmaxf(m, __shfl_down(m, off));
  const int wid = threadIdx.x >> 6, lane = threadIdx.x & 63;
  if (lane == 0) red[wid] = m;
  __syncthreads();
  float r = fmaxf(fmaxf(red[0], red[1]), fmaxf(red[2], red[3]));
  __syncthreads();
  return r;
}

// ---------------------------------------------------------------------------
// ONE cooperative kernel: amax (x||w) -> grid.sync -> local finalize (every
// block redundantly reduces 512 partials: deterministic, identical result)
// -> quant (x||w). Kills 2 launch gaps + the 1-block finalize GPU bubble;
// x stays L3-resident between the amax read and the quant read.
// Grid 512 x 256 thr = 2 blocks/CU — co-resident, cooperative-safe.
// Blocks [0,448): x; [448,512): w.
// ---------------------------------------------------------------------------
#define NBX 448
#define NBW 64

__global__ void fused_pre(const float* __restrict__ x, const float* __restrict__ wsrc,
                          const float* __restrict__ bias,
                          signed char* __restrict__ qx, signed char* __restrict__ qw,
                          float* __restrict__ px, float* __restrict__ pw,
                          float* __restrict__ amax, float* __restrict__ bdeq) {
  __shared__ float red[4];
  cg::grid_group grid = cg::this_grid();

  const int tid = threadIdx.x;
  const bool isx = blockIdx.x < NBX;
  const float* src = isx ? x : wsrc;
  signed char* dst = isx ? qx : qw;
  const int n4   = isx ? (M_ROWS * K_DIM / 4) : (N_OUT * K_DIM / 4);
  const int nblk = isx ? NBX : NBW;
  const int bidl = isx ? blockIdx.x : blockIdx.x - NBX;
  const int stride = nblk * 256;

  // ---- phase 1: partial amax ----
  float m = 0.0f;
  for (int idx = bidl * 256 + tid; idx < n4; idx += stride) {
    float4 v = ((const float4*)src)[idx];
    m = fmaxf(m, fmaxf(fmaxf(fabsf(v.x), fabsf(v.y)), fmaxf(fabsf(v.z), fabsf(v.w))));
  }
  float r = block_reduce_max4(m, red);
  if (tid == 0) (isx ? px : pw)[bidl] = r;
  __threadfence();
  grid.sync();

  // ---- phase 2: every block reduces the partials locally (identical order
  // everywhere -> identical scales; no second sync needed) ----
  m = 0.0f;
  for (int i = tid; i < NBX; i += 256) m = fmaxf(m, px[i]);
  float rx = block_reduce_max4(m, red);
  m = (tid < NBW) ? pw[tid] : 0.0f;
  float rw = block_reduce_max4(m, red);
  if (rx == 0.0f) rx = 1.0f;
  if (rw == 0.0f) rw = 1.0f;

  if (blockIdx.x == 0) {
    float4 bv = ((const float4*)bias)[tid];  // 256*4 == 1024
    m = fmaxf(fmaxf(fabsf(bv.x), fabsf(bv.y)), fmaxf(fabsf(bv.z), fabsf(bv.w)));
    float rb = block_reduce_max4(m, red);
    if (rb == 0.0f) rb = 1.0f;
    if (tid == 0) { amax[0] = rx; amax[1] = rw; amax[2] = rb; }
    const float sb = 127.0f / rb;
    float4 qv;
    qv.x = fminf(fmaxf(rintf(sb * bv.x), -127.0f), 127.0f) / sb;
    qv.y = fminf(fmaxf(rintf(sb * bv.y), -127.0f), 127.0f) / sb;
    qv.z = fminf(fmaxf(rintf(sb * bv.z), -127.0f), 127.0f) / sb;
    qv.w = fminf(fmaxf(rintf(sb * bv.w), -127.0f), 127.0f) / sb;
    ((float4*)bdeq)[tid] = qv;
  }

  // ---- phase 3: quantize (x hot in L3 from phase 1) ----
  const float s = 127.0f / (isx ? rx : rw);
  for (int idx = bidl * 256 + tid; idx < n4; idx += stride) {
    float4 v = ((const float4*)src)[idx];
    int q0 = (int)fminf(fmaxf(rintf(s * v.x), -127.0f), 127.0f);
    int q1 = (int)fminf(fmaxf(rintf(s * v.y), -127.0f), 127.0f);
    int q2 = (int)fminf(fmaxf(rintf(s * v.z), -127.0f), 127.0f);
    int q3 = (int)fminf(fmaxf(rintf(s * v.w), -127.0f), 127.0f);
    unsigned int packed = (q0 & 0xff) | ((q1 & 0xff) << 8) |
                          ((q2 & 0xff) << 16) | ((q3 & 0xff) << 24);
    ((unsigned int*)dst)[idx] = packed;
  }
}

// ---------------------------------------------------------------------------
// i8 GEMM — byte-identical to R15 (passed, absmax 0.0156): 128x128 tile,
// BK=64, 8 waves (2Mx4N, wave=64x32), triple-buffered 48KB LDS, one barrier
// per K-step {STG; VM(2); BAR; 6 ds_read; 8 MFMA}, XOR-swizzle both-sides,
// per-wave LDS-transpose + nontemporal v4f store epilogue.
// ---------------------------------------------------------------------------
#define NKT 16

__global__ __launch_bounds__(512, 4) void gemm_kernel(
    const signed char* __restrict__ qx, const signed char* __restrict__ qw,
    const float* __restrict__ amax, const float* __restrict__ bdeq,
    float* __restrict__ out) {
  __shared__ char lds[49152];  // 3 bufs x 16KB (A 8K + B 8K)

  const int tid  = threadIdx.x;
  const int w    = tid >> 6;
  const int lane = tid & 63;
  const int wm = w >> 2;   // 0..1 (64 rows)
  const int wn = w & 3;    // 0..3 (32 cols)
  const int fr = lane & 15;
  const int q  = lane >> 4;

  // XCD-aware swizzle (grid 1024 = 8 XCDs x 128 contiguous)
  const int bid = blockIdx.x;
  const int wg  = (bid & 7) * 128 + (bid >> 3);
  const int Mbase = (wg >> 3) * 128;
  const int Nbase = (wg & 7) * 128;

  const signed char* gA = qx + (size_t)Mbase * K_DIM;
  const signed char* gB = qw + (size_t)Nbase * K_DIM;

  const int scol = ((tid & 3) ^ ((tid >> 3) & 3)) << 4;
  const size_t srowK = (size_t)(tid >> 2) * K_DIM;
  const int u0 = (q ^ ((fr >> 1) & 3)) << 4;

  const float inv_denom = (amax[0] * amax[1]) * (1.0f / 16129.0f);

  v4i acc[4][2] = {};
  v4i Ar[4], Br[2];

#define STG(BASE, T)                                                           \
  do {                                                                         \
    const int _k0 = (T)*64 + scol;                                             \
    gload_lds16(gA + srowK + _k0, (BASE) + tid * 16);                          \
    gload_lds16(gB + srowK + _k0, (BASE) + 8192 + tid * 16);                   \
  } while (0)

#define VM(N) asm volatile("s_waitcnt vmcnt(" #N ")" ::: "memory")
#define LGKM0() asm volatile("s_waitcnt lgkmcnt(0)" ::: "memory")

  char* pR = lds;
  char* pS = lds + 16384;
  char* pF = lds + 32768;

  STG(pR, 0);

#pragma unroll
  for (int kt = 0; kt < NKT; ++kt) {
    if (kt + 1 < NKT) {
      STG(pS, kt + 1);
      VM(2);
    } else {
      VM(0);
    }
    __builtin_amdgcn_s_barrier();

    const char* _A = pR + wm * 4096;
    const char* _B = pR + 8192 + wn * 2048;
#pragma unroll
    for (int f = 0; f < 4; ++f)
      Ar[f] = *(const v4i*)(_A + f * 1024 + fr * 64 + u0);
#pragma unroll
    for (int g = 0; g < 2; ++g)
      Br[g] = *(const v4i*)(_B + g * 1024 + fr * 64 + u0);
#pragma unroll
    for (int f = 0; f < 4; ++f)
#pragma unroll
      for (int g = 0; g < 2; ++g)
        acc[f][g] = __builtin_amdgcn_mfma_i32_16x16x64_i8(Ar[f], Br[g], acc[f][g], 0, 0, 0);

    char* t = pR; pR = pS; pS = pF; pF = t;
  }
#undef STG

  __syncthreads();

  float bdq[2];
#pragma unroll
  for (int g = 0; g < 2; ++g) bdq[g] = bdeq[Nbase + wn * 32 + g * 16 + fr];

  float* lws = (float*)(lds + w * 4096);  // 16 x 36 f32 per wave

  const int erow = lane >> 3;
  const int ecg  = lane & 7;
  float* const orow_base = out + (size_t)(Mbase + wm * 64) * N_OUT +
                           (Nbase + wn * 32) + ecg * 4;

#pragma unroll
  for (int f = 0; f < 4; ++f) {
#pragma unroll
    for (int g = 0; g < 2; ++g)
#pragma unroll
      for (int i = 0; i < 4; ++i)
        lws[(q * 4 + i) * 36 + g * 16 + fr] =
            (float)acc[f][g][i] * inv_denom + bdq[g];
    LGKM0();
#pragma unroll
    for (int t = 0; t < 2; ++t) {
      const int r16 = t * 8 + erow;
      v4f v = *(const v4f*)&lws[r16 * 36 + ecg * 4];
      __builtin_nontemporal_store(
          v, (v4f*)(orow_base + (size_t)(f * 16 + r16) * N_OUT));
    }
    LGKM0();
  }
#undef VM
#undef LGKM0
}

extern "C" void kernel_launch(void* const* d_in, const int* in_sizes, int n_in,
                              void* d_out, int out_size, void* d_ws, size_t ws_size,
                              hipStream_t stream) {
  const float* x = (const float*)d_in[0];
  const float* w = (const float*)d_in[1];
  const float* b = (const float*)d_in[2];
  float* out = (float*)d_out;

  char* ws = (char*)d_ws;
  float* amax = (float*)ws;                             // 3 floats
  float* bdeq = (float*)(ws + 256);                     // 4 KB
  float* px   = (float*)(ws + 8192);                    // 448 partials
  float* pw   = (float*)(ws + 16384);                   // 64 partials
  signed char* qw = (signed char*)(ws + 65536);         // 1 MB
  signed char* qx = (signed char*)(ws + (1 << 21));     // 16 MB

  void* args[] = {(void*)&x, (void*)&w, (void*)&b, (void*)&qx, (void*)&qw,
                  (void*)&px, (void*)&pw, (void*)&amax, (void*)&bdeq};
  hipLaunchCooperativeKernel((const void*)fused_pre, dim3(NBX + NBW), dim3(256),
                             args, 0, stream);
  hipLaunchKernelGGL(gemm_kernel, dim3(128 * 8), dim3(512), 0, stream, qx, qw, amax, bdeq, out);
}

// Round 17
// 74.573 us; speedup vs baseline: 1.9840x; 1.9840x over previous
//
#include <hip/hip_runtime.h>

// AdaPT_Linear: per-tensor int8 quantized linear.
// out = (qx @ qw^T).f32 / (sa*sw) + qb.f32/sb
// x: [16384,1024] f32, w: [1024,1024] f32, b: [1024] f32, out: [16384,1024] f32

#define M_ROWS 16384
#define K_DIM  1024
#define N_OUT  1024

typedef int v4i __attribute__((ext_vector_type(4)));
typedef float v4f __attribute__((ext_vector_type(4)));

__device__ __forceinline__ void gload_lds16(const void* g, void* l) {
  __builtin_amdgcn_global_load_lds(
      (const __attribute__((address_space(1))) void*)g,
      (__attribute__((address_space(3))) void*)l, 16, 0, 0);
}

__device__ __forceinline__ float block_reduce_max4(float m, float* red) {
#pragma unroll
  for (int off = 32; off > 0; off >>= 1)
    m = fmaxf(m, __shfl_down(m, off));
  const int wid = threadIdx.x >> 6, lane = threadIdx.x & 63;
  if (lane == 0) red[wid] = m;
  __syncthreads();
  float r = fmaxf(fmaxf(red[0], red[1]), fmaxf(red[2], red[3]));
  __syncthreads();
  return r;
}

// fused: blocks [0,2048) reduce x -> px, blocks [2048,2304) reduce w -> pw
__global__ void amax_both(const float* __restrict__ x, const float* __restrict__ wsrc,
                          float* __restrict__ px, float* __restrict__ pw) {
  __shared__ float red[4];
  const bool isx = blockIdx.x < 2048;
  const float* src = isx ? x : wsrc;
  const int n4   = isx ? (M_ROWS * K_DIM / 4) : (N_OUT * K_DIM / 4);
  const int nblk = isx ? 2048 : 256;
  const int bidl = isx ? blockIdx.x : blockIdx.x - 2048;
  float m = 0.0f;
  const int stride = nblk * 256;
  for (int idx = bidl * 256 + threadIdx.x; idx < n4; idx += stride) {
    float4 v = ((const float4*)src)[idx];
    m = fmaxf(m, fmaxf(fmaxf(fabsf(v.x), fabsf(v.y)), fmaxf(fabsf(v.z), fabsf(v.w))));
  }
  float r = block_reduce_max4(m, red);
  if (threadIdx.x == 0) (isx ? px : pw)[bidl] = r;
}

__global__ void finalize_kernel(const float* __restrict__ px, int npx,
                                const float* __restrict__ pw, int npw,
                                const float* __restrict__ bias,
                                float* __restrict__ amax,
                                float* __restrict__ bdeq) {
  __shared__ float red[4];
  const int tid = threadIdx.x;

  float m = 0.0f;
  for (int i = tid; i < npx; i += 256) m = fmaxf(m, px[i]);
  float rx = block_reduce_max4(m, red);

  m = 0.0f;
  for (int i = tid; i < npw; i += 256) m = fmaxf(m, pw[i]);
  float rw = block_reduce_max4(m, red);

  float4 bv = ((const float4*)bias)[tid];  // 256*4 == 1024 exactly
  m = fmaxf(fmaxf(fabsf(bv.x), fabsf(bv.y)), fmaxf(fabsf(bv.z), fabsf(bv.w)));
  float rb = block_reduce_max4(m, red);

  if (rx == 0.0f) rx = 1.0f;
  if (rw == 0.0f) rw = 1.0f;
  if (rb == 0.0f) rb = 1.0f;
  if (tid == 0) {
    amax[0] = rx;
    amax[1] = rw;
    amax[2] = rb;
  }
  const float sb = 127.0f / rb;
  float4 q;
  q.x = fminf(fmaxf(rintf(sb * bv.x), -127.0f), 127.0f) / sb;
  q.y = fminf(fmaxf(rintf(sb * bv.y), -127.0f), 127.0f) / sb;
  q.z = fminf(fmaxf(rintf(sb * bv.z), -127.0f), 127.0f) / sb;
  q.w = fminf(fmaxf(rintf(sb * bv.w), -127.0f), 127.0f) / sb;
  ((float4*)bdeq)[tid] = q;
}

// fused: blocks [0,2048) quantize x -> qx, [2048,2304) w -> qw
__global__ void quant_both(const float* __restrict__ x, const float* __restrict__ wsrc,
                           signed char* __restrict__ qx, signed char* __restrict__ qw,
                           const float* __restrict__ amax) {
  const bool isx = blockIdx.x < 2048;
  const float* src = isx ? x : wsrc;
  signed char* dst = isx ? qx : qw;
  const int n4   = isx ? (M_ROWS * K_DIM / 4) : (N_OUT * K_DIM / 4);
  const int nblk = isx ? 2048 : 256;
  const int bidl = isx ? blockIdx.x : blockIdx.x - 2048;
  const float s = 127.0f / amax[isx ? 0 : 1];
  const int stride = nblk * 256;
  for (int idx = bidl * 256 + threadIdx.x; idx < n4; idx += stride) {
    float4 v = ((const float4*)src)[idx];
    int q0 = (int)fminf(fmaxf(rintf(s * v.x), -127.0f), 127.0f);
    int q1 = (int)fminf(fmaxf(rintf(s * v.y), -127.0f), 127.0f);
    int q2 = (int)fminf(fmaxf(rintf(s * v.z), -127.0f), 127.0f);
    int q3 = (int)fminf(fmaxf(rintf(s * v.w), -127.0f), 127.0f);
    unsigned int packed = (q0 & 0xff) | ((q1 & 0xff) << 8) |
                          ((q2 & 0xff) << 16) | ((q3 & 0xff) << 24);
    ((unsigned int*)dst)[idx] = packed;
  }
}

// ---------------------------------------------------------------------------
// i8 GEMM, 128x128 tile, BK=64, 8 waves (2Mx4N, wave=64x32), 512 thr.
// STRUCTURAL CHANGE vs R15: B (qw, 1MB, L2-resident) is REGISTER-DIRECT —
// never touches LDS. LDS carries only A: per-CU-kt reads 96->64KB, staging
// writes halve. (Arithmetic: LDS port @85B/cy was ~1130cy/kt vs MFMA 585 —
// port-bound; this cuts the port term by ~1/3.)
// B pipeline: pair j covers kts {2j,2j+1}, frags B[4] (2 kt x 2 col-tiles),
// loaded 2 kts ahead into alternating reg sets (Ba/Bb, static unroll).
// A pipeline: R14-proven triple-buffer single-barrier {STG; VM; BAR; rd+MFMA}.
// vmcnt ledger (1 A-stage/kt, 4 B-loads at even kt after BAR):
//   even kt: enter {A(kt),B_j(4)}=5; STG->6; VM(1) drains A(kt)+B_j (issued
//            2kt=~1200cy ago, landed) leaving A(kt+1); BAR; issue B_{j+1};
//   odd kt:  enter {A(kt),B_next(4)}=5; STG->6; VM(5) drains A(kt) only.
//   Last pair: even VM(1) ok; odd: no STG, VM(0).
// Swizzle (A only): stored unit = gunit ^ ((row>>1)&3), pre-swizzled source
// + swizzled read (involution); reads 2-way-bank = free.
// Epilogue: per-wave 16x36 LDS transpose (3KB/wave in the 24KB buffer) +
// nontemporal v4f stores. LDS total 24KB, __launch_bounds__(512,4) caps
// VGPR at 128 (est ~105) -> 2 blocks/CU, 4 waves/SIMD.
// ---------------------------------------------------------------------------
#define NKT 16

__global__ __launch_bounds__(512, 4) void gemm_kernel(
    const signed char* __restrict__ qx, const signed char* __restrict__ qw,
    const float* __restrict__ amax, const float* __restrict__ bdeq,
    float* __restrict__ out) {
  __shared__ char lds[24576];  // 3 x 8KB A bufs

  const int tid  = threadIdx.x;
  const int w    = tid >> 6;
  const int lane = tid & 63;
  const int wm = w >> 2;   // 0..1 (64 rows)
  const int wn = w & 3;    // 0..3 (32 cols)
  const int fr = lane & 15;
  const int q  = lane >> 4;

  // XCD-aware swizzle (grid 1024 = 8 XCDs x 128 contiguous)
  const int bid = blockIdx.x;
  const int wg  = (bid & 7) * 128 + (bid >> 3);
  const int Mbase = (wg >> 3) * 128;
  const int Nbase = (wg & 7) * 128;

  const signed char* gA = qx + (size_t)Mbase * K_DIM;
  // B per-lane fragment pointers (two col-tiles, 16 rows apart)
  const signed char* pb0 = qw + (size_t)(Nbase + wn * 32 + fr) * K_DIM + q * 16;
  const signed char* pb1 = pb0 + (size_t)16 * K_DIM;

  // A staging: thread t -> row t>>2 (0..127), source unit (t&3)^((t>>3)&3)
  const int scol = ((tid & 3) ^ ((tid >> 3) & 3)) << 4;
  const size_t srowK = (size_t)(tid >> 2) * K_DIM;
  // A read: stored unit q ^ ((row>>1)&3) = q ^ ((fr>>1)&3)
  const int aoff = (wm * 64 + fr) * 64 + ((q ^ ((fr >> 1) & 3)) << 4);

  const float inv_denom = (amax[0] * amax[1]) * (1.0f / 16129.0f);

  v4i acc[4][2] = {};
  v4i Ar[4];
  v4i Ba[4], Bb[4];  // alternating B pair sets (static roles)

#define STG(BASE, T)                                                           \
  gload_lds16(gA + srowK + (T)*64 + scol, (BASE) + tid * 16)

#define VM(N) asm volatile("s_waitcnt vmcnt(" #N ")" ::: "memory")
#define LGKM0() asm volatile("s_waitcnt lgkmcnt(0)" ::: "memory")

#define RD_A()                                                                 \
  do {                                                                         \
    _Pragma("unroll") for (int f = 0; f < 4; ++f)                              \
        Ar[f] = *(const v4i*)(pR + aoff + f * 1024);                           \
  } while (0)

#define MFMA2(B0v, B1v)                                                        \
  do {                                                                         \
    _Pragma("unroll") for (int f = 0; f < 4; ++f) {                            \
      acc[f][0] = __builtin_amdgcn_mfma_i32_16x16x64_i8(Ar[f], (B0v), acc[f][0], 0, 0, 0); \
      acc[f][1] = __builtin_amdgcn_mfma_i32_16x16x64_i8(Ar[f], (B1v), acc[f][1], 0, 0, 0); \
    }                                                                          \
  } while (0)

#define LOADB(SET, J2)                                                         \
  do {                                                                         \
    SET[0] = *(const v4i*)(pb0 + (J2)*64);                                     \
    SET[1] = *(const v4i*)(pb1 + (J2)*64);                                     \
    SET[2] = *(const v4i*)(pb0 + (J2 + 1) * 64);                               \
    SET[3] = *(const v4i*)(pb1 + (J2 + 1) * 64);                               \
  } while (0)

#define ROT() do { char* _t = pR; pR = pS; pS = pF; pF = _t; } while (0)

// one pair of K-steps: kts {2J, 2J+1} using BCUR; prefetch BNXT for pair J+1
#define PAIR(J, BCUR, BNXT, LAST)                                              \
  do {                                                                         \
    /* even kt = 2J */                                                         \
    STG(pS, 2 * (J) + 1);                                                      \
    VM(1);                                                                     \
    __builtin_amdgcn_s_barrier();                                              \
    if (!(LAST)) LOADB(BNXT, 2 * (J) + 2);                                     \
    RD_A();                                                                    \
    MFMA2(BCUR[0], BCUR[1]);                                                   \
    ROT();                                                                     \
    /* odd kt = 2J+1 */                                                        \
    if (!(LAST)) { STG(pS, 2 * (J) + 2); VM(5); } else { VM(0); }              \
    __builtin_amdgcn_s_barrier();                                              \
    RD_A();                                                                    \
    MFMA2(BCUR[2], BCUR[3]);                                                   \
    ROT();                                                                     \
  } while (0)

  char* pR = lds;
  char* pS = lds + 8192;
  char* pF = lds + 16384;

  // prologue: A tile0 -> buf0; B pair0 -> Ba; drain all
  STG(pR, 0);
  LOADB(Ba, 0);
  VM(0);
  __builtin_amdgcn_s_barrier();

  PAIR(0, Ba, Bb, 0);
  PAIR(1, Bb, Ba, 0);
  PAIR(2, Ba, Bb, 0);
  PAIR(3, Bb, Ba, 0);
  PAIR(4, Ba, Bb, 0);
  PAIR(5, Bb, Ba, 0);
  PAIR(6, Ba, Bb, 0);
  PAIR(7, Bb, Ba, 1);

#undef PAIR
#undef LOADB
#undef MFMA2
#undef RD_A
#undef STG
#undef ROT

  // ------------------------ epilogue (store-path) --------------------------
  __syncthreads();  // final A reads drained; repurpose LDS

  float bdq[2];
#pragma unroll
  for (int g = 0; g < 2; ++g) bdq[g] = bdeq[Nbase + wn * 32 + g * 16 + fr];

  float* lws = (float*)(lds + w * 3072);  // 16 x 36 f32 = 2304B per wave

  const int erow = lane >> 3;   // 0..7
  const int ecg  = lane & 7;    // 8 x 16B = 128B contiguous per 8 lanes
  float* const orow_base = out + (size_t)(Mbase + wm * 64) * N_OUT +
                           (Nbase + wn * 32) + ecg * 4;

#pragma unroll
  for (int f = 0; f < 4; ++f) {
#pragma unroll
    for (int g = 0; g < 2; ++g)
#pragma unroll
      for (int i = 0; i < 4; ++i)
        lws[(q * 4 + i) * 36 + g * 16 + fr] =
            (float)acc[f][g][i] * inv_denom + bdq[g];
    LGKM0();  // wave-local ordering
#pragma unroll
    for (int t = 0; t < 2; ++t) {
      const int r16 = t * 8 + erow;
      v4f v = *(const v4f*)&lws[r16 * 36 + ecg * 4];
      __builtin_nontemporal_store(
          v, (v4f*)(orow_base + (size_t)(f * 16 + r16) * N_OUT));
    }
    LGKM0();  // reads done before overwrite
  }
#undef VM
#undef LGKM0
}

extern "C" void kernel_launch(void* const* d_in, const int* in_sizes, int n_in,
                              void* d_out, int out_size, void* d_ws, size_t ws_size,
                              hipStream_t stream) {
  const float* x = (const float*)d_in[0];
  const float* w = (const float*)d_in[1];
  const float* b = (const float*)d_in[2];
  float* out = (float*)d_out;

  char* ws = (char*)d_ws;
  float* amax = (float*)ws;                             // 3 floats
  float* bdeq = (float*)(ws + 256);                     // 4 KB
  float* px   = (float*)(ws + 8192);                    // 2048 partials
  float* pw   = (float*)(ws + 16384 + 8192);            // 256 partials
  signed char* qw = (signed char*)(ws + 65536);         // 1 MB
  signed char* qx = (signed char*)(ws + (1 << 21));     // 16 MB

  const int NPX = 2048, NPW = 256;
  hipLaunchKernelGGL(amax_both, dim3(NPX + NPW), dim3(256), 0, stream, x, w, px, pw);
  hipLaunchKernelGGL(finalize_kernel, dim3(1), dim3(256), 0, stream, px, NPX, pw, NPW, b, amax, bdeq);
  hipLaunchKernelGGL(quant_both, dim3(NPX + NPW), dim3(256), 0, stream, x, w, qx, qw, amax);
  hipLaunchKernelGGL(gemm_kernel, dim3(128 * 8), dim3(512), 0, stream, qx, qw, amax, bdeq, out);
}

// Round 18
// 64.559 us; speedup vs baseline: 2.2918x; 1.1551x over previous
//
#include <hip/hip_runtime.h>

// AdaPT_Linear: per-tensor int8 quantized linear.
// out = (qx @ qw^T).f32 / (sa*sw) + qb.f32/sb
// x: [16384,1024] f32, w: [1024,1024] f32, b: [1024] f32, out: [16384,1024] f32

#define M_ROWS 16384
#define K_DIM  1024
#define N_OUT  1024

typedef int v4i __attribute__((ext_vector_type(4)));
typedef float v4f __attribute__((ext_vector_type(4)));

__device__ __forceinline__ void gload_lds16(const void* g, void* l) {
  __builtin_amdgcn_global_load_lds(
      (const __attribute__((address_space(1))) void*)g,
      (__attribute__((address_space(3))) void*)l, 16, 0, 0);
}

__device__ __forceinline__ float block_reduce_max4(float m, float* red) {
#pragma unroll
  for (int off = 32; off > 0; off >>= 1)
    m = fmaxf(m, __shfl_down(m, off));
  const int wid = threadIdx.x >> 6, lane = threadIdx.x & 63;
  if (lane == 0) red[wid] = m;
  __syncthreads();
  float r = fmaxf(fmaxf(red[0], red[1]), fmaxf(red[2], red[3]));
  __syncthreads();
  return r;
}

// fused: blocks [0,2048) reduce x -> px, blocks [2048,2304) reduce w -> pw
__global__ void amax_both(const float* __restrict__ x, const float* __restrict__ wsrc,
                          float* __restrict__ px, float* __restrict__ pw) {
  __shared__ float red[4];
  const bool isx = blockIdx.x < 2048;
  const float* src = isx ? x : wsrc;
  const int n4   = isx ? (M_ROWS * K_DIM / 4) : (N_OUT * K_DIM / 4);
  const int nblk = isx ? 2048 : 256;
  const int bidl = isx ? blockIdx.x : blockIdx.x - 2048;
  float m = 0.0f;
  const int stride = nblk * 256;
  for (int idx = bidl * 256 + threadIdx.x; idx < n4; idx += stride) {
    float4 v = ((const float4*)src)[idx];
    m = fmaxf(m, fmaxf(fmaxf(fabsf(v.x), fabsf(v.y)), fmaxf(fabsf(v.z), fabsf(v.w))));
  }
  float r = block_reduce_max4(m, red);
  if (threadIdx.x == 0) (isx ? px : pw)[bidl] = r;
}

__global__ void finalize_kernel(const float* __restrict__ px, int npx,
                                const float* __restrict__ pw, int npw,
                                const float* __restrict__ bias,
                                float* __restrict__ amax,
                                float* __restrict__ bdeq) {
  __shared__ float red[4];
  const int tid = threadIdx.x;

  float m = 0.0f;
  for (int i = tid; i < npx; i += 256) m = fmaxf(m, px[i]);
  float rx = block_reduce_max4(m, red);

  m = 0.0f;
  for (int i = tid; i < npw; i += 256) m = fmaxf(m, pw[i]);
  float rw = block_reduce_max4(m, red);

  float4 bv = ((const float4*)bias)[tid];  // 256*4 == 1024 exactly
  m = fmaxf(fmaxf(fabsf(bv.x), fabsf(bv.y)), fmaxf(fabsf(bv.z), fabsf(bv.w)));
  float rb = block_reduce_max4(m, red);

  if (rx == 0.0f) rx = 1.0f;
  if (rw == 0.0f) rw = 1.0f;
  if (rb == 0.0f) rb = 1.0f;
  if (tid == 0) {
    amax[0] = rx;
    amax[1] = rw;
    amax[2] = rb;
  }
  const float sb = 127.0f / rb;
  float4 q;
  q.x = fminf(fmaxf(rintf(sb * bv.x), -127.0f), 127.0f) / sb;
  q.y = fminf(fmaxf(rintf(sb * bv.y), -127.0f), 127.0f) / sb;
  q.z = fminf(fmaxf(rintf(sb * bv.z), -127.0f), 127.0f) / sb;
  q.w = fminf(fmaxf(rintf(sb * bv.w), -127.0f), 127.0f) / sb;
  ((float4*)bdeq)[tid] = q;
}

// fused: blocks [0,2048) quantize x -> qx, [2048,2304) w -> qw
__global__ void quant_both(const float* __restrict__ x, const float* __restrict__ wsrc,
                           signed char* __restrict__ qx, signed char* __restrict__ qw,
                           const float* __restrict__ amax) {
  const bool isx = blockIdx.x < 2048;
  const float* src = isx ? x : wsrc;
  signed char* dst = isx ? qx : qw;
  const int n4   = isx ? (M_ROWS * K_DIM / 4) : (N_OUT * K_DIM / 4);
  const int nblk = isx ? 2048 : 256;
  const int bidl = isx ? blockIdx.x : blockIdx.x - 2048;
  const float s = 127.0f / amax[isx ? 0 : 1];
  const int stride = nblk * 256;
  for (int idx = bidl * 256 + threadIdx.x; idx < n4; idx += stride) {
    float4 v = ((const float4*)src)[idx];
    int q0 = (int)fminf(fmaxf(rintf(s * v.x), -127.0f), 127.0f);
    int q1 = (int)fminf(fmaxf(rintf(s * v.y), -127.0f), 127.0f);
    int q2 = (int)fminf(fmaxf(rintf(s * v.z), -127.0f), 127.0f);
    int q3 = (int)fminf(fmaxf(rintf(s * v.w), -127.0f), 127.0f);
    unsigned int packed = (q0 & 0xff) | ((q1 & 0xff) << 8) |
                          ((q2 & 0xff) << 16) | ((q3 & 0xff) << 24);
    ((unsigned int*)dst)[idx] = packed;
  }
}

// ---------------------------------------------------------------------------
// i8 GEMM, 128x128 tile, BK=64, 8 waves (2Mx4N, wave=64x32), 512 thr.
// A-RESIDENT: the block's ENTIRE A-panel (128 rows x 1024 K = 128KB) is
// staged into LDS in the PROLOGUE (16 gload_lds/thread). The K-loop then
// carries only B staging (8KB/kt, 1 load/thread) — approximating the R12
// MODE2 regime (zero-VMEM loop = 56% MfmaUtil) that every per-kt-staged
// variant missed (all stuck at 15%). B is qw: 1MB, re-read by 128 row-block
// groups -> L2-superhot, VM(1) wait is ~L2 latency prefetched 1 kt ahead.
// LDS: A 16 x 8KB sub-tiles [kt][128 rows][64B] (= proven per-kt layout) +
// B 2 x 8KB dbuf = 144KB <= 160KB, 1 block/CU. Grid 1024 = 4 rounds/CU
// (rounds desync the store tail).
// Per kt: {STG_B(pS, kt+1); VM(1); BAR; 6 ds_read; 8 MFMA}; 2-buffer B safe
// with single barrier: reads of pR drained pre-MFMA(kt) (compiler lgkmcnt),
// MFMA(kt) precedes BAR(kt+1), stager writes pR only after BAR(kt+1).
// Swizzle (both A and B): stored 16B-unit = gunit ^ ((row>>1)&3) via
// pre-swizzled global source + swizzled ds_read (involution).
// Epilogue: per-wave 16x36 LDS transpose + nontemporal v4f stores (proven).
// ---------------------------------------------------------------------------
#define NKT 16

__global__ __launch_bounds__(512, 2) void gemm_kernel(
    const signed char* __restrict__ qx, const signed char* __restrict__ qw,
    const float* __restrict__ amax, const float* __restrict__ bdeq,
    float* __restrict__ out) {
  __shared__ char lds[147456];  // A: 16x8KB @0; B dbuf: 2x8KB @131072

  const int tid  = threadIdx.x;
  const int w    = tid >> 6;
  const int lane = tid & 63;
  const int wm = w >> 2;   // 0..1 (64 rows)
  const int wn = w & 3;    // 0..3 (32 cols)
  const int fr = lane & 15;
  const int q  = lane >> 4;

  // XCD-aware swizzle (grid 1024 = 8 XCDs x 128 contiguous)
  const int bid = blockIdx.x;
  const int wg  = (bid & 7) * 128 + (bid >> 3);
  const int Mbase = (wg >> 3) * 128;
  const int Nbase = (wg & 7) * 128;

  const signed char* gA = qx + (size_t)Mbase * K_DIM;
  const signed char* gB = qw + (size_t)Nbase * K_DIM;

  // staging: thread t -> row t>>2 (0..127), source unit (t&3)^((t>>3)&3)
  const int scol = ((tid & 3) ^ ((tid >> 3) & 3)) << 4;
  const size_t srowK = (size_t)(tid >> 2) * K_DIM;
  // fragment read: row R -> stored unit q ^ ((R>>1)&3) = q ^ ((fr>>1)&3)
  const int u0 = (q ^ ((fr >> 1) & 3)) << 4;

  const float inv_denom = (amax[0] * amax[1]) * (1.0f / 16129.0f);

  v4i acc[4][2] = {};
  v4i Ar[4], Br[2];

#define STG_B(BASE, T)                                                         \
  gload_lds16(gB + srowK + (T)*64 + scol, (BASE) + tid * 16)

#define VM(N) asm volatile("s_waitcnt vmcnt(" #N ")" ::: "memory")
#define LGKM0() asm volatile("s_waitcnt lgkmcnt(0)" ::: "memory")

  char* pR = lds + 131072;          // B read buffer (tile kt)
  char* pS = lds + 131072 + 8192;   // B stage target (tile kt+1)

  // ---- prologue: ALL of A (16 sub-tiles) + B tile0 ----
#pragma unroll
  for (int kt2 = 0; kt2 < NKT; ++kt2)
    gload_lds16(gA + srowK + kt2 * 64 + scol, lds + kt2 * 8192 + tid * 16);
  STG_B(pR, 0);
  VM(0);
  __builtin_amdgcn_s_barrier();

#pragma unroll
  for (int kt = 0; kt < NKT; ++kt) {
    if (kt + 1 < NKT) {
      STG_B(pS, kt + 1);
      VM(1);  // this wave's B(kt) landed (1 just-issued remains)
    } else {
      VM(0);
    }
    __builtin_amdgcn_s_barrier();  // publish all waves' B(kt) slices

    const char* _A = lds + kt * 8192 + wm * 4096;  // 64 rows x 64B
    const char* _B = pR + wn * 2048;               // 32 rows x 64B
#pragma unroll
    for (int f = 0; f < 4; ++f)
      Ar[f] = *(const v4i*)(_A + f * 1024 + fr * 64 + u0);
#pragma unroll
    for (int g = 0; g < 2; ++g)
      Br[g] = *(const v4i*)(_B + g * 1024 + fr * 64 + u0);
#pragma unroll
    for (int f = 0; f < 4; ++f)
#pragma unroll
      for (int g = 0; g < 2; ++g)
        acc[f][g] = __builtin_amdgcn_mfma_i32_16x16x64_i8(Ar[f], Br[g], acc[f][g], 0, 0, 0);

    char* t = pR; pR = pS; pS = t;  // swap B buffers
  }
#undef STG_B

  // ------------------------ epilogue (store-path) --------------------------
  __syncthreads();  // final reads drained; repurpose LDS

  float bdq[2];
#pragma unroll
  for (int g = 0; g < 2; ++g) bdq[g] = bdeq[Nbase + wn * 32 + g * 16 + fr];

  float* lws = (float*)(lds + w * 3072);  // 16 x 36 f32 = 2304B per wave

  const int erow = lane >> 3;   // 0..7
  const int ecg  = lane & 7;    // 8 x 16B = 128B contiguous per 8 lanes
  float* const orow_base = out + (size_t)(Mbase + wm * 64) * N_OUT +
                           (Nbase + wn * 32) + ecg * 4;

#pragma unroll
  for (int f = 0; f < 4; ++f) {
#pragma unroll
    for (int g = 0; g < 2; ++g)
#pragma unroll
      for (int i = 0; i < 4; ++i)
        lws[(q * 4 + i) * 36 + g * 16 + fr] =
            (float)acc[f][g][i] * inv_denom + bdq[g];
    LGKM0();  // wave-local ordering
#pragma unroll
    for (int t = 0; t < 2; ++t) {
      const int r16 = t * 8 + erow;
      v4f v = *(const v4f*)&lws[r16 * 36 + ecg * 4];
      __builtin_nontemporal_store(
          v, (v4f*)(orow_base + (size_t)(f * 16 + r16) * N_OUT));
    }
    LGKM0();  // reads done before overwrite
  }
#undef VM
#undef LGKM0
}

extern "C" void kernel_launch(void* const* d_in, const int* in_sizes, int n_in,
                              void* d_out, int out_size, void* d_ws, size_t ws_size,
                              hipStream_t stream) {
  const float* x = (const float*)d_in[0];
  const float* w = (const float*)d_in[1];
  const float* b = (const float*)d_in[2];
  float* out = (float*)d_out;

  char* ws = (char*)d_ws;
  float* amax = (float*)ws;                             // 3 floats
  float* bdeq = (float*)(ws + 256);                     // 4 KB
  float* px   = (float*)(ws + 8192);                    // 2048 partials
  float* pw   = (float*)(ws + 16384 + 8192);            // 256 partials
  signed char* qw = (signed char*)(ws + 65536);         // 1 MB
  signed char* qx = (signed char*)(ws + (1 << 21));     // 16 MB

  const int NPX = 2048, NPW = 256;
  hipLaunchKernelGGL(amax_both, dim3(NPX + NPW), dim3(256), 0, stream, x, w, px, pw);
  hipLaunchKernelGGL(finalize_kernel, dim3(1), dim3(256), 0, stream, px, NPX, pw, NPW, b, amax, bdeq);
  hipLaunchKernelGGL(quant_both, dim3(NPX + NPW), dim3(256), 0, stream, x, w, qx, qw, amax);
  hipLaunchKernelGGL(gemm_kernel, dim3(128 * 8), dim3(512), 0, stream, qx, qw, amax, bdeq, out);
}

// Round 19
// 59.094 us; speedup vs baseline: 2.5037x; 1.0925x over previous
//
#include <hip/hip_runtime.h>

// AdaPT_Linear: per-tensor int8 quantized linear.
// out = (qx @ qw^T).f32 / (sa*sw) + qb.f32/sb
// x: [16384,1024] f32, w: [1024,1024] f32, b: [1024] f32, out: [16384,1024] f32

#define M_ROWS 16384
#define K_DIM  1024
#define N_OUT  1024

typedef int v4i __attribute__((ext_vector_type(4)));
typedef float v4f __attribute__((ext_vector_type(4)));

__device__ __forceinline__ void gload_lds16(const void* g, void* l) {
  __builtin_amdgcn_global_load_lds(
      (const __attribute__((address_space(1))) void*)g,
      (__attribute__((address_space(3))) void*)l, 16, 0, 0);
}

__device__ __forceinline__ float block_reduce_max4(float m, float* red) {
#pragma unroll
  for (int off = 32; off > 0; off >>= 1)
    m = fmaxf(m, __shfl_down(m, off));
  const int wid = threadIdx.x >> 6, lane = threadIdx.x & 63;
  if (lane == 0) red[wid] = m;
  __syncthreads();
  float r = fmaxf(fmaxf(red[0], red[1]), fmaxf(red[2], red[3]));
  __syncthreads();
  return r;
}

// fused: blocks [0,2048) reduce x -> px, blocks [2048,2304) reduce w -> pw
__global__ void amax_both(const float* __restrict__ x, const float* __restrict__ wsrc,
                          float* __restrict__ px, float* __restrict__ pw) {
  __shared__ float red[4];
  const bool isx = blockIdx.x < 2048;
  const float* src = isx ? x : wsrc;
  const int n4   = isx ? (M_ROWS * K_DIM / 4) : (N_OUT * K_DIM / 4);
  const int nblk = isx ? 2048 : 256;
  const int bidl = isx ? blockIdx.x : blockIdx.x - 2048;
  float m = 0.0f;
  const int stride = nblk * 256;
  for (int idx = bidl * 256 + threadIdx.x; idx < n4; idx += stride) {
    float4 v = ((const float4*)src)[idx];
    m = fmaxf(m, fmaxf(fmaxf(fabsf(v.x), fabsf(v.y)), fmaxf(fabsf(v.z), fabsf(v.w))));
  }
  float r = block_reduce_max4(m, red);
  if (threadIdx.x == 0) (isx ? px : pw)[bidl] = r;
}

__global__ void finalize_kernel(const float* __restrict__ px, int npx,
                                const float* __restrict__ pw, int npw,
                                const float* __restrict__ bias,
                                float* __restrict__ amax,
                                float* __restrict__ bdeq) {
  __shared__ float red[4];
  const int tid = threadIdx.x;

  float m = 0.0f;
  for (int i = tid; i < npx; i += 256) m = fmaxf(m, px[i]);
  float rx = block_reduce_max4(m, red);

  m = 0.0f;
  for (int i = tid; i < npw; i += 256) m = fmaxf(m, pw[i]);
  float rw = block_reduce_max4(m, red);

  float4 bv = ((const float4*)bias)[tid];  // 256*4 == 1024 exactly
  m = fmaxf(fmaxf(fabsf(bv.x), fabsf(bv.y)), fmaxf(fabsf(bv.z), fabsf(bv.w)));
  float rb = block_reduce_max4(m, red);

  if (rx == 0.0f) rx = 1.0f;
  if (rw == 0.0f) rw = 1.0f;
  if (rb == 0.0f) rb = 1.0f;
  if (tid == 0) {
    amax[0] = rx;
    amax[1] = rw;
    amax[2] = rb;
  }
  const float sb = 127.0f / rb;
  float4 q;
  q.x = fminf(fmaxf(rintf(sb * bv.x), -127.0f), 127.0f) / sb;
  q.y = fminf(fmaxf(rintf(sb * bv.y), -127.0f), 127.0f) / sb;
  q.z = fminf(fmaxf(rintf(sb * bv.z), -127.0f), 127.0f) / sb;
  q.w = fminf(fmaxf(rintf(sb * bv.w), -127.0f), 127.0f) / sb;
  ((float4*)bdeq)[tid] = q;
}

// fused: blocks [0,2048) quantize x -> qx, [2048,2304) w -> qw
__global__ void quant_both(const float* __restrict__ x, const float* __restrict__ wsrc,
                           signed char* __restrict__ qx, signed char* __restrict__ qw,
                           const float* __restrict__ amax) {
  const bool isx = blockIdx.x < 2048;
  const float* src = isx ? x : wsrc;
  signed char* dst = isx ? qx : qw;
  const int n4   = isx ? (M_ROWS * K_DIM / 4) : (N_OUT * K_DIM / 4);
  const int nblk = isx ? 2048 : 256;
  const int bidl = isx ? blockIdx.x : blockIdx.x - 2048;
  const float s = 127.0f / amax[isx ? 0 : 1];
  const int stride = nblk * 256;
  for (int idx = bidl * 256 + threadIdx.x; idx < n4; idx += stride) {
    float4 v = ((const float4*)src)[idx];
    int q0 = (int)fminf(fmaxf(rintf(s * v.x), -127.0f), 127.0f);
    int q1 = (int)fminf(fmaxf(rintf(s * v.y), -127.0f), 127.0f);
    int q2 = (int)fminf(fmaxf(rintf(s * v.z), -127.0f), 127.0f);
    int q3 = (int)fminf(fmaxf(rintf(s * v.w), -127.0f), 127.0f);
    unsigned int packed = (q0 & 0xff) | ((q1 & 0xff) << 8) |
                          ((q2 & 0xff) << 16) | ((q3 & 0xff) << 24);
    ((unsigned int*)dst)[idx] = packed;
  }
}

// ---------------------------------------------------------------------------
// i8 GEMM, 128x128 tile, BK=64, 8 waves (2Mx4N, wave=64x32), 512 thr,
// triple-buffered 48KB LDS, single-barrier K-loop — VERBATIM from R15
// (passed twice, absmax 0.0156). NEW: block-cooperative WIDE-SEGMENT store
// epilogue. Evidence: staging 3.3us + MFMA-core 13.2us but full always
// ~40us -> ~23us is the store path; old epilogue issued 32 stores/thread of
// 8x128B scattered segments per 64-lane instr (fills hitting 6.7TB/s write
// 4KB contiguous/instr). Now: 8 passes over 16-row groups; owning 4 waves
// scatter scaled acc into a 16x132 f32 LDS buffer; sync; ALL 8 waves issue
// ONE v4f store instr = 2 rows x 512B contiguous segments. 8 store
// instrs/wave total (was 32), 512B segments (was 128B).
// ---------------------------------------------------------------------------
#define NKT 16

__global__ __launch_bounds__(512, 4) void gemm_kernel(
    const signed char* __restrict__ qx, const signed char* __restrict__ qw,
    const float* __restrict__ amax, const float* __restrict__ bdeq,
    float* __restrict__ out) {
  __shared__ char lds[49152];  // 3 bufs x 16KB (A 8K + B 8K)

  const int tid  = threadIdx.x;
  const int w    = tid >> 6;
  const int lane = tid & 63;
  const int wm = w >> 2;   // 0..1 (64 rows)
  const int wn = w & 3;    // 0..3 (32 cols)
  const int fr = lane & 15;
  const int q  = lane >> 4;

  // XCD-aware swizzle (grid 1024 = 8 XCDs x 128 contiguous)
  const int bid = blockIdx.x;
  const int wg  = (bid & 7) * 128 + (bid >> 3);
  const int Mbase = (wg >> 3) * 128;
  const int Nbase = (wg & 7) * 128;

  const signed char* gA = qx + (size_t)Mbase * K_DIM;
  const signed char* gB = qw + (size_t)Nbase * K_DIM;

  const int scol = ((tid & 3) ^ ((tid >> 3) & 3)) << 4;
  const size_t srowK = (size_t)(tid >> 2) * K_DIM;
  const int u0 = (q ^ ((fr >> 1) & 3)) << 4;

  const float inv_denom = (amax[0] * amax[1]) * (1.0f / 16129.0f);

  v4i acc[4][2] = {};
  v4i Ar[4], Br[2];

#define STG(BASE, T)                                                           \
  do {                                                                         \
    const int _k0 = (T)*64 + scol;                                             \
    gload_lds16(gA + srowK + _k0, (BASE) + tid * 16);                          \
    gload_lds16(gB + srowK + _k0, (BASE) + 8192 + tid * 16);                   \
  } while (0)

#define VM(N) asm volatile("s_waitcnt vmcnt(" #N ")" ::: "memory")

  char* pR = lds;
  char* pS = lds + 16384;
  char* pF = lds + 32768;

  STG(pR, 0);

#pragma unroll
  for (int kt = 0; kt < NKT; ++kt) {
    if (kt + 1 < NKT) {
      STG(pS, kt + 1);
      VM(2);
    } else {
      VM(0);
    }
    __builtin_amdgcn_s_barrier();

    const char* _A = pR + wm * 4096;
    const char* _B = pR + 8192 + wn * 2048;
#pragma unroll
    for (int f = 0; f < 4; ++f)
      Ar[f] = *(const v4i*)(_A + f * 1024 + fr * 64 + u0);
#pragma unroll
    for (int g = 0; g < 2; ++g)
      Br[g] = *(const v4i*)(_B + g * 1024 + fr * 64 + u0);
#pragma unroll
    for (int f = 0; f < 4; ++f)
#pragma unroll
      for (int g = 0; g < 2; ++g)
        acc[f][g] = __builtin_amdgcn_mfma_i32_16x16x64_i8(Ar[f], Br[g], acc[f][g], 0, 0, 0);

    char* t = pR; pR = pS; pS = pF; pF = t;
  }
#undef STG
#undef VM

  // ------------- epilogue: block-cooperative wide-segment stores -----------
  __syncthreads();  // K-loop reads drained; repurpose lds[0..8448)

  float bdq[2];
#pragma unroll
  for (int g = 0; g < 2; ++g) bdq[g] = bdeq[Nbase + wn * 32 + g * 16 + fr];

  float* lws = (float*)lds;  // 16 rows x 132 f32 (stride 528B, 16B-aligned)

  const int srow2 = lane >> 5;        // 0..1
  const int sc4   = (lane & 31) * 4;  // 4-col group: 32 lanes cover 128 cols

#pragma unroll
  for (int p = 0; p < 8; ++p) {
    // writers: waves with wm == p>>2 scatter f = p&3 (16 rows x 128 cols)
    if (wm == (p >> 2)) {
      const int f = p & 3;
#pragma unroll
      for (int g = 0; g < 2; ++g)
#pragma unroll
        for (int i = 0; i < 4; ++i)
          lws[(q * 4 + i) * 132 + wn * 32 + g * 16 + fr] =
              (float)acc[f][g][i] * inv_denom + bdq[g];
    }
    __syncthreads();
    // all 8 waves: one v4f store instr = rows {2w, 2w+1}, 512B contiguous/row
    {
      const int r = (w << 1) | srow2;
      v4f v = *(const v4f*)&lws[r * 132 + sc4];
      __builtin_nontemporal_store(
          v, (v4f*)(out + (size_t)(Mbase + p * 16 + r) * N_OUT + Nbase + sc4));
    }
    __syncthreads();
  }
}

extern "C" void kernel_launch(void* const* d_in, const int* in_sizes, int n_in,
                              void* d_out, int out_size, void* d_ws, size_t ws_size,
                              hipStream_t stream) {
  const float* x = (const float*)d_in[0];
  const float* w = (const float*)d_in[1];
  const float* b = (const float*)d_in[2];
  float* out = (float*)d_out;

  char* ws = (char*)d_ws;
  float* amax = (float*)ws;                             // 3 floats
  float* bdeq = (float*)(ws + 256);                     // 4 KB
  float* px   = (float*)(ws + 8192);                    // 2048 partials
  float* pw   = (float*)(ws + 16384 + 8192);            // 256 partials
  signed char* qw = (signed char*)(ws + 65536);         // 1 MB
  signed char* qx = (signed char*)(ws + (1 << 21));     // 16 MB

  const int NPX = 2048, NPW = 256;
  hipLaunchKernelGGL(amax_both, dim3(NPX + NPW), dim3(256), 0, stream, x, w, px, pw);
  hipLaunchKernelGGL(finalize_kernel, dim3(1), dim3(256), 0, stream, px, NPX, pw, NPW, b, amax, bdeq);
  hipLaunchKernelGGL(quant_both, dim3(NPX + NPW), dim3(256), 0, stream, x, w, qx, qw, amax);
  hipLaunchKernelGGL(gemm_kernel, dim3(128 * 8), dim3(512), 0, stream, qx, qw, amax, bdeq, out);
}

// Round 20
// 56.439 us; speedup vs baseline: 2.6215x; 1.0471x over previous
//
#include <hip/hip_runtime.h>

// AdaPT_Linear: per-tensor int8 quantized linear.
// out = (qx @ qw^T).f32 / (sa*sw) + qb.f32/sb
// x: [16384,1024] f32, w: [1024,1024] f32, b: [1024] f32, out: [16384,1024] f32

#define M_ROWS 16384
#define K_DIM  1024
#define N_OUT  1024

typedef int v4i __attribute__((ext_vector_type(4)));
typedef float v4f __attribute__((ext_vector_type(4)));

__device__ __forceinline__ void gload_lds16(const void* g, void* l) {
  __builtin_amdgcn_global_load_lds(
      (const __attribute__((address_space(1))) void*)g,
      (__attribute__((address_space(3))) void*)l, 16, 0, 0);
}

__device__ __forceinline__ float block_reduce_max4(float m, float* red) {
#pragma unroll
  for (int off = 32; off > 0; off >>= 1)
    m = fmaxf(m, __shfl_down(m, off));
  const int wid = threadIdx.x >> 6, lane = threadIdx.x & 63;
  if (lane == 0) red[wid] = m;
  __syncthreads();
  float r = fmaxf(fmaxf(red[0], red[1]), fmaxf(red[2], red[3]));
  __syncthreads();
  return r;
}

// K1: blocks [0,2048) reduce x -> px, blocks [2048,2304) reduce w -> pw
__global__ void amax_both(const float* __restrict__ x, const float* __restrict__ wsrc,
                          float* __restrict__ px, float* __restrict__ pw) {
  __shared__ float red[4];
  const bool isx = blockIdx.x < 2048;
  const float* src = isx ? x : wsrc;
  const int n4   = isx ? (M_ROWS * K_DIM / 4) : (N_OUT * K_DIM / 4);
  const int nblk = isx ? 2048 : 256;
  const int bidl = isx ? blockIdx.x : blockIdx.x - 2048;
  float m = 0.0f;
  const int stride = nblk * 256;
  for (int idx = bidl * 256 + threadIdx.x; idx < n4; idx += stride) {
    float4 v = ((const float4*)src)[idx];
    m = fmaxf(m, fmaxf(fmaxf(fabsf(v.x), fabsf(v.y)), fmaxf(fabsf(v.z), fabsf(v.w))));
  }
  float r = block_reduce_max4(m, red);
  if (threadIdx.x == 0) (isx ? px : pw)[bidl] = r;
}

// K2: finalize folded into quant — EVERY block redundantly reduces the 2304
// partials (deterministic identical order -> bit-identical scales), then
// quantizes its slice. Block 2304 computes bias amax + bdeq + amax[] for the
// gemm. Removes the 1-block finalize kernel (255-CU bubble) + one launch gap.
__global__ void quant_fin(const float* __restrict__ x, const float* __restrict__ wsrc,
                          const float* __restrict__ bias,
                          signed char* __restrict__ qx, signed char* __restrict__ qw,
                          const float* __restrict__ px, const float* __restrict__ pw,
                          float* __restrict__ amax, float* __restrict__ bdeq) {
  __shared__ float red[4];
  const int tid = threadIdx.x;

  // local finalize (partials are >= 0; px: 512 float4, pw: 64 float4)
  float m = 0.0f;
#pragma unroll
  for (int i = 0; i < 2; ++i) {
    float4 v = ((const float4*)px)[tid + i * 256];
    m = fmaxf(m, fmaxf(fmaxf(v.x, v.y), fmaxf(v.z, v.w)));
  }
  float rx = block_reduce_max4(m, red);
  m = 0.0f;
  if (tid < 64) {
    float4 v = ((const float4*)pw)[tid];
    m = fmaxf(fmaxf(v.x, v.y), fmaxf(v.z, v.w));
  }
  float rw = block_reduce_max4(m, red);
  if (rx == 0.0f) rx = 1.0f;
  if (rw == 0.0f) rw = 1.0f;

  if (blockIdx.x == 2304) {  // bias block: amax[] + dequantized bias
    float4 bv = ((const float4*)bias)[tid];  // 256*4 == 1024
    m = fmaxf(fmaxf(fabsf(bv.x), fabsf(bv.y)), fmaxf(fabsf(bv.z), fabsf(bv.w)));
    float rb = block_reduce_max4(m, red);
    if (rb == 0.0f) rb = 1.0f;
    if (tid == 0) { amax[0] = rx; amax[1] = rw; amax[2] = rb; }
    const float sb = 127.0f / rb;
    float4 q;
    q.x = fminf(fmaxf(rintf(sb * bv.x), -127.0f), 127.0f) / sb;
    q.y = fminf(fmaxf(rintf(sb * bv.y), -127.0f), 127.0f) / sb;
    q.z = fminf(fmaxf(rintf(sb * bv.z), -127.0f), 127.0f) / sb;
    q.w = fminf(fmaxf(rintf(sb * bv.w), -127.0f), 127.0f) / sb;
    ((float4*)bdeq)[tid] = q;
    return;
  }

  const bool isx = blockIdx.x < 2048;
  const float* src = isx ? x : wsrc;
  signed char* dst = isx ? qx : qw;
  const int n4   = isx ? (M_ROWS * K_DIM / 4) : (N_OUT * K_DIM / 4);
  const int nblk = isx ? 2048 : 256;
  const int bidl = isx ? blockIdx.x : blockIdx.x - 2048;
  const float s = 127.0f / (isx ? rx : rw);
  const int stride = nblk * 256;
  for (int idx = bidl * 256 + tid; idx < n4; idx += stride) {
    float4 v = ((const float4*)src)[idx];
    int q0 = (int)fminf(fmaxf(rintf(s * v.x), -127.0f), 127.0f);
    int q1 = (int)fminf(fmaxf(rintf(s * v.y), -127.0f), 127.0f);
    int q2 = (int)fminf(fmaxf(rintf(s * v.z), -127.0f), 127.0f);
    int q3 = (int)fminf(fmaxf(rintf(s * v.w), -127.0f), 127.0f);
    unsigned int packed = (q0 & 0xff) | ((q1 & 0xff) << 8) |
                          ((q2 & 0xff) << 16) | ((q3 & 0xff) << 24);
    ((unsigned int*)dst)[idx] = packed;
  }
}

// ---------------------------------------------------------------------------
// i8 GEMM — byte-identical to R19 (passed, absmax 0.0156): 128x128 tile,
// BK=64, 8 waves (2Mx4N, wave=64x32), triple-buffered 48KB LDS,
// single-barrier K-loop {STG; VM(2); BAR; 6 ds_read; 8 MFMA}, XOR-swizzle
// both-sides, block-cooperative wide-segment store epilogue (512B segments).
// ---------------------------------------------------------------------------
#define NKT 16

__global__ __launch_bounds__(512, 4) void gemm_kernel(
    const signed char* __restrict__ qx, const signed char* __restrict__ qw,
    const float* __restrict__ amax, const float* __restrict__ bdeq,
    float* __restrict__ out) {
  __shared__ char lds[49152];  // 3 bufs x 16KB (A 8K + B 8K)

  const int tid  = threadIdx.x;
  const int w    = tid >> 6;
  const int lane = tid & 63;
  const int wm = w >> 2;   // 0..1 (64 rows)
  const int wn = w & 3;    // 0..3 (32 cols)
  const int fr = lane & 15;
  const int q  = lane >> 4;

  // XCD-aware swizzle (grid 1024 = 8 XCDs x 128 contiguous)
  const int bid = blockIdx.x;
  const int wg  = (bid & 7) * 128 + (bid >> 3);
  const int Mbase = (wg >> 3) * 128;
  const int Nbase = (wg & 7) * 128;

  const signed char* gA = qx + (size_t)Mbase * K_DIM;
  const signed char* gB = qw + (size_t)Nbase * K_DIM;

  const int scol = ((tid & 3) ^ ((tid >> 3) & 3)) << 4;
  const size_t srowK = (size_t)(tid >> 2) * K_DIM;
  const int u0 = (q ^ ((fr >> 1) & 3)) << 4;

  const float inv_denom = (amax[0] * amax[1]) * (1.0f / 16129.0f);

  v4i acc[4][2] = {};
  v4i Ar[4], Br[2];

#define STG(BASE, T)                                                           \
  do {                                                                         \
    const int _k0 = (T)*64 + scol;                                             \
    gload_lds16(gA + srowK + _k0, (BASE) + tid * 16);                          \
    gload_lds16(gB + srowK + _k0, (BASE) + 8192 + tid * 16);                   \
  } while (0)

#define VM(N) asm volatile("s_waitcnt vmcnt(" #N ")" ::: "memory")

  char* pR = lds;
  char* pS = lds + 16384;
  char* pF = lds + 32768;

  STG(pR, 0);

#pragma unroll
  for (int kt = 0; kt < NKT; ++kt) {
    if (kt + 1 < NKT) {
      STG(pS, kt + 1);
      VM(2);
    } else {
      VM(0);
    }
    __builtin_amdgcn_s_barrier();

    const char* _A = pR + wm * 4096;
    const char* _B = pR + 8192 + wn * 2048;
#pragma unroll
    for (int f = 0; f < 4; ++f)
      Ar[f] = *(const v4i*)(_A + f * 1024 + fr * 64 + u0);
#pragma unroll
    for (int g = 0; g < 2; ++g)
      Br[g] = *(const v4i*)(_B + g * 1024 + fr * 64 + u0);
#pragma unroll
    for (int f = 0; f < 4; ++f)
#pragma unroll
      for (int g = 0; g < 2; ++g)
        acc[f][g] = __builtin_amdgcn_mfma_i32_16x16x64_i8(Ar[f], Br[g], acc[f][g], 0, 0, 0);

    char* t = pR; pR = pS; pS = pF; pF = t;
  }
#undef STG
#undef VM

  // ------------- epilogue: block-cooperative wide-segment stores -----------
  __syncthreads();  // K-loop reads drained; repurpose lds[0..8448)

  float bdq[2];
#pragma unroll
  for (int g = 0; g < 2; ++g) bdq[g] = bdeq[Nbase + wn * 32 + g * 16 + fr];

  float* lws = (float*)lds;  // 16 rows x 132 f32 (stride 528B, 16B-aligned)

  const int srow2 = lane >> 5;        // 0..1
  const int sc4   = (lane & 31) * 4;  // 4-col group: 32 lanes cover 128 cols

#pragma unroll
  for (int p = 0; p < 8; ++p) {
    // writers: waves with wm == p>>2 scatter f = p&3 (16 rows x 128 cols)
    if (wm == (p >> 2)) {
      const int f = p & 3;
#pragma unroll
      for (int g = 0; g < 2; ++g)
#pragma unroll
        for (int i = 0; i < 4; ++i)
          lws[(q * 4 + i) * 132 + wn * 32 + g * 16 + fr] =
              (float)acc[f][g][i] * inv_denom + bdq[g];
    }
    __syncthreads();
    // all 8 waves: one v4f store instr = rows {2w, 2w+1}, 512B contiguous/row
    {
      const int r = (w << 1) | srow2;
      v4f v = *(const v4f*)&lws[r * 132 + sc4];
      __builtin_nontemporal_store(
          v, (v4f*)(out + (size_t)(Mbase + p * 16 + r) * N_OUT + Nbase + sc4));
    }
    __syncthreads();
  }
}

extern "C" void kernel_launch(void* const* d_in, const int* in_sizes, int n_in,
                              void* d_out, int out_size, void* d_ws, size_t ws_size,
                              hipStream_t stream) {
  const float* x = (const float*)d_in[0];
  const float* w = (const float*)d_in[1];
  const float* b = (const float*)d_in[2];
  float* out = (float*)d_out;

  char* ws = (char*)d_ws;
  float* amax = (float*)ws;                             // 3 floats
  float* bdeq = (float*)(ws + 256);                     // 4 KB
  float* px   = (float*)(ws + 8192);                    // 2048 partials
  float* pw   = (float*)(ws + 16384 + 8192);            // 256 partials
  signed char* qw = (signed char*)(ws + 65536);         // 1 MB
  signed char* qx = (signed char*)(ws + (1 << 21));     // 16 MB

  const int NPX = 2048, NPW = 256;
  hipLaunchKernelGGL(amax_both, dim3(NPX + NPW), dim3(256), 0, stream, x, w, px, pw);
  hipLaunchKernelGGL(quant_fin, dim3(NPX + NPW + 1), dim3(256), 0, stream,
                     x, w, b, qx, qw, px, pw, amax, bdeq);
  hipLaunchKernelGGL(gemm_kernel, dim3(128 * 8), dim3(512), 0, stream, qx, qw, amax, bdeq, out);
}